// Round 3
// baseline (167.935 us; speedup 1.0000x reference)
//
#include <hip/hip_runtime.h>

#define D 128
#define LIST_CAP 1024

// LDS layout (floats): P[16384] | U[8*128] | R[8*128] | part[16] | list[1024] | El[8] | cnt[1]
#define SMEM_FLOATS (16384 + 1024 + 1024 + 16 + 1024 + 8 + 1)
#define SMEM_BYTES (SMEM_FLOATS * 4)

__global__ __launch_bounds__(512, 4) void transr_fused(
    const float* __restrict__ head,
    const float* __restrict__ tail,
    const float* __restrict__ edge,
    const float* __restrict__ proj,
    const int* __restrict__ idx,
    float* __restrict__ out,
    int B)
{
    const int rel = blockIdx.x;
    const int tid = threadIdx.x;

    extern __shared__ float sm[];
    float* Pl   = sm;                  // 16384, XOR-swizzled quads
    float* Ul   = sm + 16384;          // 8 x 128
    float* Rl   = sm + 17408;          // 8 x 128
    float* part = sm + 18432;          // [2][8]
    int*   list = (int*)(sm + 18448);  // 1024
    int*   El   = (int*)(sm + 19472);  // 8
    int*   cnt  = (int*)(sm + 19480);  // 1

    if (tid == 0) *cnt = 0;

    // ---- issue P global loads early (latency overlap with idx scan) ----
    const float4* __restrict__ Pg =
        reinterpret_cast<const float4*>(proj + (size_t)rel * (D * D));
    float4 stg[8];
    #pragma unroll
    for (int i = 0; i < 8; ++i) stg[i] = Pg[tid + 512 * i];

    __syncthreads();   // cnt initialized

    // ---- self-bucketing: scan idx for elements of this relation ----
    const int4* __restrict__ idx4 = reinterpret_cast<const int4*>(idx);
    const int nv = B >> 2;
    for (int f = tid; f < nv; f += 512) {
        const int4 v = idx4[f];
        if (v.x == rel) { int p = atomicAdd(cnt, 1); if (p < LIST_CAP) list[p] = 4 * f + 0; }
        if (v.y == rel) { int p = atomicAdd(cnt, 1); if (p < LIST_CAP) list[p] = 4 * f + 1; }
        if (v.z == rel) { int p = atomicAdd(cnt, 1); if (p < LIST_CAP) list[p] = 4 * f + 2; }
        if (v.w == rel) { int p = atomicAdd(cnt, 1); if (p < LIST_CAP) list[p] = 4 * f + 3; }
    }
    __syncthreads();
    const int n = min(*cnt, LIST_CAP);
    if (n == 0) return;

    // ---- write P to LDS, swizzled: quad q of row -> phys quad q^(row&31) ----
    #pragma unroll
    for (int i = 0; i < 8; ++i) {
        const int f = tid + 512 * i;
        const int row = f >> 5;
        const int q = f & 31;
        *reinterpret_cast<float4*>(Pl + row * D + 4 * (q ^ (row & 31))) = stg[i];
    }

    const int w    = tid >> 6;   // wave 0..7
    const int wl   = tid & 63;
    const int e0   = 2 * (w & 3);
    const int e1   = e0 + 1;
    const int half = w >> 2;     // row half
    const int row  = half * 64 + wl;
    const float* Prow = Pl + row * D;
    const int sx = wl & 31;

    const int nchunk = (n + 7) >> 3;
    for (int ch = 0; ch < nchunk; ++ch) {
        // ---- Phase A: wave w normalizes element ch*8+w; u = h/|h| - t/|t| ----
        const int e = ch * 8 + w;
        int b = -1;
        float2 u2 = make_float2(0.f, 0.f);
        float2 r2 = make_float2(0.f, 0.f);
        if (e < n) {
            b = list[e];
            const float2 h2 = *reinterpret_cast<const float2*>(head + (size_t)b * D + 2 * wl);
            const float2 t2 = *reinterpret_cast<const float2*>(tail + (size_t)b * D + 2 * wl);
            r2 = *reinterpret_cast<const float2*>(edge + (size_t)b * D + 2 * wl);
            float hs = h2.x * h2.x + h2.y * h2.y;
            float ts = t2.x * t2.x + t2.y * t2.y;
            #pragma unroll
            for (int m = 1; m < 64; m <<= 1) {
                hs += __shfl_xor(hs, m);
                ts += __shfl_xor(ts, m);
            }
            const float hn = fmaxf(sqrtf(hs), 1e-12f);
            const float tn = fmaxf(sqrtf(ts), 1e-12f);
            u2.x = h2.x / hn - t2.x / tn;
            u2.y = h2.y / hn - t2.y / tn;
        }
        *reinterpret_cast<float2*>(Ul + w * D + 2 * wl) = u2;
        *reinterpret_cast<float2*>(Rl + w * D + 2 * wl) = r2;
        if (wl == 0) El[w] = b;
        __syncthreads();

        // ---- Phase B: wave w: elements e0,e1 x rows [half*64, half*64+64) ----
        float acc0 = 0.f, acc1 = 0.f;
        const float* U0 = Ul + e0 * D;
        const float* U1 = Ul + e1 * D;
        #pragma unroll
        for (int q = 0; q < 32; ++q) {
            const float4 p = *reinterpret_cast<const float4*>(Prow + 4 * (q ^ sx));
            const float4 a = *reinterpret_cast<const float4*>(U0 + 4 * q);  // wave-uniform: broadcast
            const float4 c = *reinterpret_cast<const float4*>(U1 + 4 * q);
            acc0 = fmaf(p.x, a.x, acc0); acc0 = fmaf(p.y, a.y, acc0);
            acc0 = fmaf(p.z, a.z, acc0); acc0 = fmaf(p.w, a.w, acc0);
            acc1 = fmaf(p.x, c.x, acc1); acc1 = fmaf(p.y, c.y, acc1);
            acc1 = fmaf(p.z, c.z, acc1); acc1 = fmaf(p.w, c.w, acc1);
        }
        const float d0 = acc0 + Rl[e0 * D + row];
        const float d1 = acc1 + Rl[e1 * D + row];
        float s0 = d0 * d0;
        float s1 = d1 * d1;
        #pragma unroll
        for (int m = 1; m < 64; m <<= 1) {
            s0 += __shfl_xor(s0, m);
            s1 += __shfl_xor(s1, m);
        }
        if (wl == 0) {
            part[half * 8 + e0] = s0;
            part[half * 8 + e1] = s1;
        }
        __syncthreads();

        // ---- write scores for this chunk ----
        if (tid < 8) {
            const int bb = El[tid];
            if (bb >= 0) out[bb] = -(part[tid] + part[8 + tid]);
        }
        __syncthreads();   // protect El/part/U/R from next chunk's Phase A
    }
}

extern "C" void kernel_launch(void* const* d_in, const int* in_sizes, int n_in,
                              void* d_out, int out_size, void* d_ws, size_t ws_size,
                              hipStream_t stream) {
    const float* head = (const float*)d_in[0];
    const float* tail = (const float*)d_in[1];
    const float* edge = (const float*)d_in[2];
    const float* proj = (const float*)d_in[3];
    const int*   idx  = (const int*)d_in[4];
    float* out = (float*)d_out;

    const int B    = in_sizes[0] / D;          // 16384
    const int nrel = in_sizes[3] / (D * D);    // 1000

    hipFuncSetAttribute(reinterpret_cast<const void*>(transr_fused),
                        hipFuncAttributeMaxDynamicSharedMemorySize, SMEM_BYTES);
    transr_fused<<<nrel, 512, SMEM_BYTES, stream>>>(head, tail, edge, proj,
                                                    idx, out, B);
}

// Round 4
// 146.616 us; speedup vs baseline: 1.1454x; 1.1454x over previous
//
#include <hip/hip_runtime.h>
#include <stdint.h>

#define D 128
#define LIST_CAP 256

// LDS floats: P[16384] | U[8*128] | R[8*128] | part[16] | list[256] | El[8] | cnt[1]
#define SMEM_FLOATS (16384 + 1024 + 1024 + 16 + LIST_CAP + 8 + 1)
#define SMEM_BYTES (SMEM_FLOATS * 4)

__global__ __launch_bounds__(512, 4) void transr_fused(
    const float* __restrict__ head,
    const float* __restrict__ tail,
    const float* __restrict__ edge,
    const float* __restrict__ proj,
    const int* __restrict__ idx,
    float* __restrict__ out,
    int B)
{
    const int rel = blockIdx.x;
    const int tid = threadIdx.x;

    extern __shared__ float sm[];
    float* Pl   = sm;                  // 16384, XOR-swizzled quads (phys)
    float* Ul   = sm + 16384;          // 8 x 128
    float* Rl   = sm + 17408;          // 8 x 128
    float* part = sm + 18432;          // [2][8]
    int*   list = (int*)(sm + 18448);  // 256
    int*   El   = (int*)(sm + 18704);  // 8
    int*   cnt  = (int*)(sm + 18712);  // 1

    if (tid == 0) *cnt = 0;

    // ---- stage P via global_load_lds: linear LDS dest, pre-swizzled global src ----
    // quad f (0..4095): row = f>>5, logical quad at phys f is q = (f&31); its data
    // comes from global quad (f&31)^(row&31). Read side XORs with the same key.
    const float* __restrict__ Pg = proj + (size_t)rel * (D * D);
    #pragma unroll
    for (int i = 0; i < 8; ++i) {
        const int f   = i * 512 + tid;          // quad index; wave-contiguous dest
        const int row = f >> 5;
        const int q   = f & 31;
        const float* src = Pg + row * D + 4 * (q ^ (row & 31));
        float* dst = Pl + 4 * f;
        __builtin_amdgcn_global_load_lds(
            (const __attribute__((address_space(1))) uint32_t*)src,
            (__attribute__((address_space(3))) uint32_t*)dst,
            16, 0, 0);
    }

    __syncthreads();   // cnt visible (P loads still in flight; drained by next sync)

    // ---- self-bucketing: scan idx for this relation (overlaps P loads) ----
    const int4* __restrict__ idx4 = reinterpret_cast<const int4*>(idx);
    const int nv = B >> 2;
    for (int f = tid; f < nv; f += 512) {
        const int4 v = idx4[f];
        if (v.x == rel) { int p = atomicAdd(cnt, 1); if (p < LIST_CAP) list[p] = 4 * f + 0; }
        if (v.y == rel) { int p = atomicAdd(cnt, 1); if (p < LIST_CAP) list[p] = 4 * f + 1; }
        if (v.z == rel) { int p = atomicAdd(cnt, 1); if (p < LIST_CAP) list[p] = 4 * f + 2; }
        if (v.w == rel) { int p = atomicAdd(cnt, 1); if (p < LIST_CAP) list[p] = 4 * f + 3; }
    }
    __syncthreads();   // list ready AND vmcnt(0): P fully in LDS
    const int n = min(*cnt, LIST_CAP);
    if (n == 0) return;

    const int w    = tid >> 6;   // wave 0..7
    const int wl   = tid & 63;
    const int e0   = 2 * (w & 3);
    const int e1   = e0 + 1;
    const int half = w >> 2;     // row half
    const int row  = half * 64 + wl;
    const float* Prow = Pl + row * D;
    const int sx = wl & 31;      // == row & 31

    const int nchunk = (n + 7) >> 3;
    for (int ch = 0; ch < nchunk; ++ch) {
        // ---- Phase A: wave w normalizes element ch*8+w; u = h/|h| - t/|t| ----
        const int e = ch * 8 + w;
        int b = -1;
        float2 u2 = make_float2(0.f, 0.f);
        float2 r2 = make_float2(0.f, 0.f);
        if (e < n) {
            b = list[e];
            const float2 h2 = *reinterpret_cast<const float2*>(head + (size_t)b * D + 2 * wl);
            const float2 t2 = *reinterpret_cast<const float2*>(tail + (size_t)b * D + 2 * wl);
            r2 = *reinterpret_cast<const float2*>(edge + (size_t)b * D + 2 * wl);
            float hs = h2.x * h2.x + h2.y * h2.y;
            float ts = t2.x * t2.x + t2.y * t2.y;
            #pragma unroll
            for (int m = 1; m < 64; m <<= 1) {
                hs += __shfl_xor(hs, m);
                ts += __shfl_xor(ts, m);
            }
            const float hn = fmaxf(sqrtf(hs), 1e-12f);
            const float tn = fmaxf(sqrtf(ts), 1e-12f);
            u2.x = h2.x / hn - t2.x / tn;
            u2.y = h2.y / hn - t2.y / tn;
        }
        *reinterpret_cast<float2*>(Ul + w * D + 2 * wl) = u2;
        *reinterpret_cast<float2*>(Rl + w * D + 2 * wl) = r2;
        if (wl == 0) El[w] = b;
        __syncthreads();

        // ---- Phase B: wave w: elements e0,e1 x rows [half*64, half*64+64) ----
        float acc0 = 0.f, acc1 = 0.f;
        const float* U0 = Ul + e0 * D;
        const float* U1 = Ul + e1 * D;
        #pragma unroll
        for (int q = 0; q < 32; ++q) {
            const float4 p = *reinterpret_cast<const float4*>(Prow + 4 * (q ^ sx));
            const float4 a = *reinterpret_cast<const float4*>(U0 + 4 * q);  // uniform: broadcast
            const float4 c = *reinterpret_cast<const float4*>(U1 + 4 * q);
            acc0 = fmaf(p.x, a.x, acc0); acc0 = fmaf(p.y, a.y, acc0);
            acc0 = fmaf(p.z, a.z, acc0); acc0 = fmaf(p.w, a.w, acc0);
            acc1 = fmaf(p.x, c.x, acc1); acc1 = fmaf(p.y, c.y, acc1);
            acc1 = fmaf(p.z, c.z, acc1); acc1 = fmaf(p.w, c.w, acc1);
        }
        const float d0 = acc0 + Rl[e0 * D + row];
        const float d1 = acc1 + Rl[e1 * D + row];
        float s0 = d0 * d0;
        float s1 = d1 * d1;
        #pragma unroll
        for (int m = 1; m < 64; m <<= 1) {
            s0 += __shfl_xor(s0, m);
            s1 += __shfl_xor(s1, m);
        }
        if (wl == 0) {
            part[half * 8 + e0] = s0;
            part[half * 8 + e1] = s1;
        }
        __syncthreads();

        // ---- write scores for this chunk ----
        if (tid < 8) {
            const int bb = El[tid];
            if (bb >= 0) out[bb] = -(part[tid] + part[8 + tid]);
        }
        __syncthreads();   // protect El/part/U/R before next chunk's Phase A
    }
}

extern "C" void kernel_launch(void* const* d_in, const int* in_sizes, int n_in,
                              void* d_out, int out_size, void* d_ws, size_t ws_size,
                              hipStream_t stream) {
    const float* head = (const float*)d_in[0];
    const float* tail = (const float*)d_in[1];
    const float* edge = (const float*)d_in[2];
    const float* proj = (const float*)d_in[3];
    const int*   idx  = (const int*)d_in[4];
    float* out = (float*)d_out;

    const int B    = in_sizes[0] / D;          // 16384
    const int nrel = in_sizes[3] / (D * D);    // 1000

    hipFuncSetAttribute(reinterpret_cast<const void*>(transr_fused),
                        hipFuncAttributeMaxDynamicSharedMemorySize, SMEM_BYTES);
    transr_fused<<<nrel, 512, SMEM_BYTES, stream>>>(head, tail, edge, proj,
                                                    idx, out, B);
}